// Round 9
// baseline (112.218 us; speedup 1.0000x reference)
//
#include <hip/hip_runtime.h>
#include <math.h>

// ---- problem constants ----
#define SEQ 64
#define NSAMP 16384
#define NHARM 32
#define NWS 512
#define NSTEP 256
#define BE 128            // B*E = 8*16
#define NFRAMES 8192      // BE * SEQ
#define GRID_NB 512u      // fused kernel grid; co-residency: LDS 34.8KB -> 4 blk/CU

typedef _Float16 half8 __attribute__((ext_vector_type(8)));
typedef float f32x4 __attribute__((ext_vector_type(4)));

__device__ __forceinline__ float sin_rev(float x) {  // sin(2*pi*x)
  float r; asm("v_sin_f32 %0, %1" : "=v"(r) : "v"(x)); return r;
}
__device__ __forceinline__ float cos_rev(float x) {  // cos(2*pi*x)
  float r; asm("v_cos_f32 %0, %1" : "=v"(r) : "v"(x)); return r;
}
__device__ __forceinline__ float clip01(float v) { return fminf(fmaxf(v, 0.0f), 1.0f); }

__device__ __forceinline__ float f0_to_norm(float f0v, float bl) {
  const float NYQ = 11025.0f;
  const float MIN_F0 = 20.0f / 11025.0f;
  const float F0_DIFF = 780.0f / 11025.0f;
  float v = fminf(fmaxf(f0v, -0.5f), 0.5f);
  float erb = (0.108f * (bl * NYQ) + 24.7f) / NYQ;
  float fv = clip01(bl + v * erb);
  return MIN_F0 + fv * F0_DIFF;
}

// Device-wide barrier: counter in global ws (zeroed per call via memset).
// All GRID_NB blocks are co-resident (LDS-capacity argument), so spin is safe.
__device__ __forceinline__ void grid_bar(unsigned int* cnt) {
  __syncthreads();
  if (threadIdx.x == 0) {
    __threadfence();  // agent-scope release of this block's global writes
    __hip_atomic_fetch_add(cnt, 1u, __ATOMIC_ACQ_REL, __HIP_MEMORY_SCOPE_AGENT);
    while (__hip_atomic_load(cnt, __ATOMIC_ACQUIRE, __HIP_MEMORY_SCOPE_AGENT) < GRID_NB) {
      __builtin_amdgcn_s_sleep(2);
    }
  }
  __syncthreads();
}

// ---------------------------------------------------------------------------
// Fused kernel: phase 0 = W1/W2 twiddle gen; phase 1 = fwd GEMM + Gaussian
// filter -> AB (f16); phase 2 = inv GEMM + overlap-add + oscillator bank +
// final mix -> out. 512 blocks x 256 threads, two grid barriers.
// ---------------------------------------------------------------------------
__global__ __launch_bounds__(256, 3) void fused_k(
    const float* __restrict__ Af,        // noise_frames [8192][512] f32
    const float* __restrict__ f0,
    const float* __restrict__ nstd,
    const float* __restrict__ f0b,
    const float* __restrict__ oenv_g,
    const float* __restrict__ oscenv_g,
    const float* __restrict__ henv_g,
    _Float16* __restrict__ W1,           // [256][512]
    _Float16* __restrict__ W2,           // [512][256]
    _Float16* __restrict__ AB,           // [8192][256]
    unsigned int* __restrict__ bar,      // [2] barrier counters (pre-zeroed)
    float* __restrict__ out) {
  __shared__ __align__(16) unsigned char smem[34816];
  const int bid = blockIdx.x;
  const int tid = threadIdx.x;
  const int wave = tid >> 6, lane = tid & 63;
  const int r = lane & 15, q = lane >> 4;

  // ================= phase 0: twiddle tables =================
  if (bid < 256) {  // W1 row bid: cos rows 0..127, sin rows 128..255
    const int k = bid & 127;
    const bool isSin = bid >= 128;
    for (int n = tid; n < 512; n += 256) {
      int a = (k * n) & 511;
      float ph = (float)a * (1.0f / 512.0f);
      W1[bid * 512 + n] = (_Float16)(isSin ? sin_rev(ph) : cos_rev(ph));
    }
  }
  {  // W2 row bid (512 rows over 512 blocks): [cos k<128 | sin k<128]
    const int k = tid & 127;
    const bool isSin = tid >= 128;
    int a = (k * bid) & 511;
    float ph = (float)a * (1.0f / 512.0f);
    W2[bid * 256 + tid] = (_Float16)(isSin ? sin_rev(ph) : cos_rev(ph));
  }

  grid_bar(&bar[0]);

  // ================= phase 1: forward GEMM + filter =================
  {
    // swizzled decode: 4 bn-blocks of one m-stripe share index mod 8 (XCD)
    const int x = bid & 7, j = bid >> 3;
    const int mstripe = ((j >> 2) << 3) + x;
    const int bn0 = (j & 3) * 64;
    const int m0 = mstripe * 64;
    const int Kt = 512;

    _Float16* Ash = (_Float16*)smem;             // [2][64*64]
    _Float16* Bsh = (_Float16*)(smem + 16384);   // [2][64*64]
    float* whann = (float*)(smem + 32768);       // [512]

    const int nT = Kt >> 6;
    const int srow0 = tid >> 3, srow1 = (256 + tid) >> 3;
    const int skg = tid & 7;

    half8 ra[2], rb[2];
    f32x4 acc[4] = {};

    whann[tid] = 0.5f - 0.5f * cos_rev((float)tid * (1.0f / 512.0f));
    whann[tid + 256] = 0.5f - 0.5f * cos_rev((float)(tid + 256) * (1.0f / 512.0f));
    __syncthreads();

    auto load_a = [&](int kk) {
      const float* s0 = Af + (size_t)(m0 + srow0) * Kt + kk + skg * 8;
      const float* s1 = Af + (size_t)(m0 + srow1) * Kt + kk + skg * 8;
      float4 a0 = ((const float4*)s0)[0], a1 = ((const float4*)s0)[1];
      float4 b0 = ((const float4*)s1)[0], b1 = ((const float4*)s1)[1];
      float4 w0 = *(const float4*)(&whann[kk + skg * 8]);
      float4 w1 = *(const float4*)(&whann[kk + skg * 8 + 4]);
      ra[0][0] = (_Float16)(a0.x * w0.x); ra[0][1] = (_Float16)(a0.y * w0.y);
      ra[0][2] = (_Float16)(a0.z * w0.z); ra[0][3] = (_Float16)(a0.w * w0.w);
      ra[0][4] = (_Float16)(a1.x * w1.x); ra[0][5] = (_Float16)(a1.y * w1.y);
      ra[0][6] = (_Float16)(a1.z * w1.z); ra[0][7] = (_Float16)(a1.w * w1.w);
      ra[1][0] = (_Float16)(b0.x * w0.x); ra[1][1] = (_Float16)(b0.y * w0.y);
      ra[1][2] = (_Float16)(b0.z * w0.z); ra[1][3] = (_Float16)(b0.w * w0.w);
      ra[1][4] = (_Float16)(b1.x * w1.x); ra[1][5] = (_Float16)(b1.y * w1.y);
      ra[1][6] = (_Float16)(b1.z * w1.z); ra[1][7] = (_Float16)(b1.w * w1.w);
      rb[0] = *(const half8*)(W1 + (size_t)(bn0 + srow0) * Kt + kk + skg * 8);
      rb[1] = *(const half8*)(W1 + (size_t)(bn0 + srow1) * Kt + kk + skg * 8);
    };
    auto store_lds = [&](int b) {
      *(half8*)(&Ash[b * 4096 + srow0 * 64 + ((skg ^ (srow0 & 7)) << 3)]) = ra[0];
      *(half8*)(&Ash[b * 4096 + srow1 * 64 + ((skg ^ (srow1 & 7)) << 3)]) = ra[1];
      *(half8*)(&Bsh[b * 4096 + srow0 * 64 + ((skg ^ (srow0 & 7)) << 3)]) = rb[0];
      *(half8*)(&Bsh[b * 4096 + srow1 * 64 + ((skg ^ (srow1 & 7)) << 3)]) = rb[1];
    };

    load_a(0);
    store_lds(0);

    for (int t = 0;;) {
      if (t + 1 < nT) load_a((t + 1) << 6);
      __syncthreads();
      const int b = t & 1;
#pragma unroll
      for (int ks = 0; ks < 2; ++ks) {
        const int swz = ((ks * 4 + q) ^ (r & 7)) << 3;
        half8 af = *(const half8*)(&Ash[b * 4096 + (wave * 16 + r) * 64 + swz]);
        half8 bf0 = *(const half8*)(&Bsh[b * 4096 + (0 * 16 + r) * 64 + swz]);
        half8 bf1 = *(const half8*)(&Bsh[b * 4096 + (1 * 16 + r) * 64 + swz]);
        half8 bf2 = *(const half8*)(&Bsh[b * 4096 + (2 * 16 + r) * 64 + swz]);
        half8 bf3 = *(const half8*)(&Bsh[b * 4096 + (3 * 16 + r) * 64 + swz]);
        acc[0] = __builtin_amdgcn_mfma_f32_16x16x32_f16(af, bf0, acc[0], 0, 0, 0);
        acc[1] = __builtin_amdgcn_mfma_f32_16x16x32_f16(af, bf1, acc[1], 0, 0, 0);
        acc[2] = __builtin_amdgcn_mfma_f32_16x16x32_f16(af, bf2, acc[2], 0, 0, 0);
        acc[3] = __builtin_amdgcn_mfma_f32_16x16x32_f16(af, bf3, acc[3], 0, 0, 0);
      }
      if (t + 1 >= nT) break;
      __syncthreads();
      store_lds((t + 1) & 1);
      ++t;
    }

    const float F0_DIFF = 780.0f / 11025.0f;
#pragma unroll
    for (int reg = 0; reg < 4; ++reg) {
      const int row = m0 + wave * 16 + q * 4 + reg;   // frame
      const float mu = f0_to_norm(f0[row], f0b[row >> 6]);
      const float sd = fminf(fmaxf(nstd[row], 1e-12f), 1.0f) * F0_DIFF;
      const float inv_sd = 1.0f / sd;
      const float a = inv_sd * (1.0f / 256.0f);
      const float bmu = mu * inv_sd;
#pragma unroll
      for (int ni = 0; ni < 4; ++ni) {
        const int col = bn0 + ni * 16 + r;             // kappa
        const int k = col & 127;
        float z = fmaf((float)k, a, -bmu);
        float cf = (k == 0) ? (1.0f / 512.0f) : (2.0f / 512.0f);
        float s = cf * exp2f(z * z * -0.72134752044f);  // exp(-z^2/2)
        AB[(size_t)row * 256 + col] = (_Float16)(acc[ni][reg] * s);
      }
    }
  }

  grid_bar(&bar[1]);

  // ================= phase 2: inverse GEMM + OLA + oscillator + mix ========
  {
    const int x = bid & 7, j = bid >> 3;
    const int be = ((j >> 2) << 3) + x;      // [0,128)
    const int n0 = (j & 3) * 64;             // sample-within-chunk base
    const int m0 = be * 64;                  // global chunk base

    _Float16* A2sh = (_Float16*)smem;            // [65*64]
    _Float16* B1sh = (_Float16*)(smem + 8320);   // [64*64]
    _Float16* B2sh = (_Float16*)(smem + 16512);  // [64*64]
    float4* qe4 = (float4*)(smem + 24704);       // [8*64]
    float* oenv = (float*)(smem + 32896);
    float* oscE = (float*)(smem + 33152);
    float* Fs = (float*)(smem + 33408);
    float* Ds = (float*)(smem + 33664);
    float* Gs = (float*)(smem + 33920);

    if (tid < SEQ) {
      oenv[tid] = clip01(oenv_g[be * SEQ + tid]);
      oscE[tid] = clip01(oscenv_g[be * SEQ + tid]);
      Fs[tid] = f0_to_norm(f0[be * SEQ + tid], f0b[be]);
    }
    __syncthreads();

    // wave 0: segment phase-prefix scan (f64, 6 shuffle steps), mod 2
    if (tid < SEQ) {
      const int s = tid;
      float fcur = Fs[s];
      float fnxt = (s < 63) ? Fs[s + 1] : Fs[63];
      Ds[s] = fnxt - fcur;                               // D[63] = 0
      double term = 128.0 * ((double)fcur + (double)fnxt);
      double sc = term;
#pragma unroll
      for (int off = 1; off < 64; off <<= 1) {
        double u = __shfl_up(sc, off, 64);
        if (s >= off) sc += u;
      }
      double C = 128.0 * (double)Fs[0] + (sc - term);    // exclusive prefix
      Gs[s] = (float)(C - 2.0 * floor(C * 0.5));
    }

    // stage qe4 (osc_env * harm_env)
    for (int idx = tid; idx < 8 * SEQ; idx += 256) {
      int hq = idx >> 6, s = idx & 63;
      const float* hb = henv_g + (size_t)be * (NHARM * SEQ) + (4 * hq) * SEQ + s;
      float e = oscE[s];
      qe4[idx] = make_float4(e * clip01(hb[0]), e * clip01(hb[64]),
                             e * clip01(hb[128]), e * clip01(hb[192]));
    }

    auto stage_AB = [&](int kk) {
#pragma unroll
      for (int it = 0; it < 3; ++it) {
        int g = it * 256 + tid;
        if (g < 520) {
          int row = g >> 3, kg = g & 7;
          half8 v = {0, 0, 0, 0, 0, 0, 0, 0};
          if (row > 0)
            v = *(const half8*)(AB + (size_t)(m0 - 1 + row) * 256 + kk + kg * 8);
          *(half8*)(&A2sh[row * 64 + ((kg ^ (row & 7)) << 3)]) = v;
        }
      }
#pragma unroll
      for (int it = 0; it < 4; ++it) {
        int g = it * 256 + tid;
        int row = (g >> 3) & 63, kg = g & 7;
        bool second = g >= 512;
        int wrow = n0 + row + (second ? 256 : 0);
        half8 v = *(const half8*)(W2 + (size_t)wrow * 256 + kk + kg * 8);
        _Float16* dst = second ? B2sh : B1sh;
        *(half8*)(&dst[row * 64 + ((kg ^ (row & 7)) << 3)]) = v;
      }
    };

    f32x4 acc[4] = {};
    stage_AB(0);
    __syncthreads();

    for (int t = 0;;) {
#pragma unroll
      for (int ks = 0; ks < 2; ++ks) {
        const int kg = ks * 4 + q;
        const int ra1 = 1 + wave * 16 + r;
        const int ra2 = wave * 16 + r;
        half8 af1 = *(const half8*)(&A2sh[ra1 * 64 + ((kg ^ (ra1 & 7)) << 3)]);
        half8 af2 = *(const half8*)(&A2sh[ra2 * 64 + ((kg ^ (ra2 & 7)) << 3)]);
#pragma unroll
        for (int ni = 0; ni < 4; ++ni) {
          const int rb = ni * 16 + r;
          const int sw = (kg ^ (rb & 7)) << 3;
          half8 bf1 = *(const half8*)(&B1sh[rb * 64 + sw]);
          half8 bf2 = *(const half8*)(&B2sh[rb * 64 + sw]);
          acc[ni] = __builtin_amdgcn_mfma_f32_16x16x32_f16(af1, bf1, acc[ni], 0, 0, 0);
          acc[ni] = __builtin_amdgcn_mfma_f32_16x16x32_f16(af2, bf2, acc[ni], 0, 0, 0);
        }
      }
      if (t == 3) break;
      __syncthreads();
      stage_AB((t + 1) << 6);
      __syncthreads();
      ++t;
    }

    // epilogue: analytic phase + oscillator bank + mix, in-register
#pragma unroll
    for (int reg = 0; reg < 4; ++reg) {
      const int c = wave * 16 + q * 4 + reg;           // chunk within be
#pragma unroll
      for (int ni = 0; ni < 4; ++ni) {
        const int n = n0 + ni * 16 + r;
        const int t = c * 256 + n;
        float pos = ((float)t + 0.5f) * (1.0f / 256.0f) - 0.5f;
        pos = fminf(fmaxf(pos, 0.0f), 63.0f);
        int i0 = (int)pos;
        int i1 = min(i0 + 1, 63);
        float w = pos - (float)i0;

        float pph;
        if (t < 128) {
          pph = (float)(t + 1) * Fs[0];
        } else {
          int s = (t - 128) >> 8;
          float u1 = (float)((t - 128) - (s << 8) + 1);
          pph = Gs[s] + fmaf(Ds[s] * (1.0f / 512.0f), u1 * u1, u1 * Fs[s]);
        }
        pph = pph - 2.0f * floorf(pph * 0.5f);         // phase mod 2 (pi units)
        float xv = pph * 0.5f;
        float sb = sin_rev(xv);
        float cb = cos_rev(xv);
        float C = 2.0f * cb;

        float fund = sb * (oscE[i0] * (1.0f - w) + oscE[i1] * w);
        float d0 = 0.0f, d1 = 0.0f;
        float sp = sb;
        float scur = C * sb;
#pragma unroll
        for (int hq = 0; hq < 8; ++hq) {
          float4 qa = qe4[hq * 64 + i0];
          float4 qb = qe4[hq * 64 + i1];
          d0 = fmaf(scur, qa.x, d0); d1 = fmaf(scur, qb.x, d1);
          sp = fmaf(C, scur, -sp);
          d0 = fmaf(sp, qa.y, d0);   d1 = fmaf(sp, qb.y, d1);
          scur = fmaf(C, sp, -scur);
          d0 = fmaf(scur, qa.z, d0); d1 = fmaf(scur, qb.z, d1);
          sp = fmaf(C, scur, -sp);
          d0 = fmaf(sp, qa.w, d0);   d1 = fmaf(sp, qb.w, d1);
          scur = fmaf(C, sp, -scur);
        }
        float osc = fund + d0 * (1.0f - w) + d1 * w;
        float mix = oenv[i0] * (1.0f - w) + oenv[i1] * w;
        out[(size_t)be * NSAMP + t] = fmaf(osc, mix, acc[ni][reg] * (1.0f - mix));
      }
    }
  }
}

// ---------------------------------------------------------------------------
extern "C" void kernel_launch(void* const* d_in, const int* in_sizes, int n_in,
                              void* d_out, int out_size, void* d_ws, size_t ws_size,
                              hipStream_t stream) {
  const float* f0           = (const float*)d_in[0];
  const float* overall_env  = (const float*)d_in[1];
  const float* osc_env      = (const float*)d_in[2];
  // d_in[3] = noise_env: unused by the reference
  const float* harm_env     = (const float*)d_in[4];
  const float* noise_std    = (const float*)d_in[5];
  const float* f0_base      = (const float*)d_in[6];
  const float* noise_frames = (const float*)d_in[7];
  float* out = (float*)d_out;

  // workspace layout
  _Float16* W1 = (_Float16*)d_ws;                         // 131,072 f16
  _Float16* W2 = W1 + 256 * 512;                          // 131,072 f16
  _Float16* AB = W2 + 512 * 256;                          // 2,097,152 f16
  unsigned int* bar = (unsigned int*)(AB + (size_t)NFRAMES * 256);  // 2 u32

  // zero the grid-barrier counters (deterministic across graph replays)
  hipMemsetAsync(bar, 0, 2 * sizeof(unsigned int), stream);

  fused_k<<<GRID_NB, 256, 0, stream>>>(
      noise_frames, f0, noise_std, f0_base, overall_env, osc_env, harm_env,
      W1, W2, AB, bar, out);
}

// Round 10
// 34.544 us; speedup vs baseline: 3.2486x; 3.2486x over previous
//
#include <hip/hip_runtime.h>
#include <math.h>

// ---- problem constants ----
#define SEQ 64
#define NSAMP 16384
#define NHARM 32
#define NWS 512
#define NSTEP 256
#define BE 128            // B*E = 8*16
#define NFRAMES 8192      // BE * SEQ

typedef _Float16 half8 __attribute__((ext_vector_type(8)));
typedef float f32x4 __attribute__((ext_vector_type(4)));

__device__ __forceinline__ float sin_rev(float x) {  // sin(2*pi*x)
  float r; asm("v_sin_f32 %0, %1" : "=v"(r) : "v"(x)); return r;
}
__device__ __forceinline__ float cos_rev(float x) {  // cos(2*pi*x)
  float r; asm("v_cos_f32 %0, %1" : "=v"(r) : "v"(x)); return r;
}
__device__ __forceinline__ float clip01(float v) { return fminf(fmaxf(v, 0.0f), 1.0f); }

__device__ __forceinline__ float f0_to_norm(float f0v, float bl) {
  const float NYQ = 11025.0f;
  const float MIN_F0 = 20.0f / 11025.0f;
  const float F0_DIFF = 780.0f / 11025.0f;
  float v = fminf(fmaxf(f0v, -0.5f), 0.5f);
  float erb = (0.108f * (bl * NYQ) + 24.7f) / NYQ;
  float fv = clip01(bl + v * erb);
  return MIN_F0 + fv * F0_DIFF;
}

// ---------------------------------------------------------------------------
// Kernel 1: prep — W1 twiddles only (256 blocks).
// ---------------------------------------------------------------------------
__global__ __launch_bounds__(256) void prep_k(_Float16* __restrict__ W1) {
  const int m = blockIdx.x, k = m & 127;
  const int tid = threadIdx.x;
  const bool isSin = m >= 128;
  for (int n = tid; n < 512; n += 256) {
    int a = (k * n) & 511;
    float ph = (float)a * (1.0f / 512.0f);
    W1[m * 512 + n] = (_Float16)(isSin ? sin_rev(ph) : cos_rev(ph));
  }
}

// ---------------------------------------------------------------------------
// Kernel 2: forward GEMM (32x64 tiles, 1024 blocks -> 4 blk/CU) + W2 gen.
//   blocks [0,256):   W2[512][256] twiddles (2 rows/block; consumer is the
//                     NEXT launch -> no race).
//   blocks [256,1280): AB[8192][256] = filt( hann(frames) x W1^T ), f16 out.
//     32-row M-tile; XCD swizzle: the 4 bn-blocks of one 32-frame stripe
//     share physical index mod 8 -> same XCD -> frame re-reads are L2 hits.
// ---------------------------------------------------------------------------
__global__ __launch_bounds__(256) void gemmf_k(const float* __restrict__ Af,
                                               const _Float16* __restrict__ B,
                                               _Float16* __restrict__ Cout,
                                               _Float16* __restrict__ W2,
                                               const float* __restrict__ f0,
                                               const float* __restrict__ nstd,
                                               const float* __restrict__ f0b) {
  const int tid = threadIdx.x;

  if (blockIdx.x < 256) {   // ---- W2 generation ----
    const int k = tid & 127;
    const bool isSin = tid >= 128;
#pragma unroll
    for (int rr = 0; rr < 2; ++rr) {
      const int n = blockIdx.x * 2 + rr;
      int a = (k * n) & 511;
      float ph = (float)a * (1.0f / 512.0f);
      W2[n * 256 + tid] = (_Float16)(isSin ? sin_rev(ph) : cos_rev(ph));
    }
    return;
  }

  // ---- GEMM: swizzled block decode (1024 blocks) ----
  const int p = blockIdx.x - 256;          // [0,1024)
  const int x = p & 7, j = p >> 3;         // j in [0,128)
  const int mstripe = ((j >> 2) << 3) + x; // [0,256)
  const int bn0 = (j & 3) * 64;
  const int m0 = mstripe * 32;

  const int Kt = 512;
  const int wave = tid >> 6, lane = tid & 63;
  const int r = lane & 15, q = lane >> 4;
  const int wr = (wave & 1) * 16;          // A-row (frame) sub-tile
  const int wc = (wave >> 1) * 32;         // B-row (kappa) sub-tile
  __shared__ __align__(16) _Float16 Ash[2][32 * 64];   // 8 KB
  __shared__ __align__(16) _Float16 Bsh[2][64 * 64];   // 16 KB
  __shared__ __align__(16) float whann[512];           // 2 KB

  const int nT = Kt >> 6;
  const int srowA = tid >> 3;              // 0..31 (one granule per thread)
  const int srowB0 = tid >> 3, srowB1 = (256 + tid) >> 3;
  const int skg = tid & 7;

  half8 ra, rb[2];
  f32x4 acc[2] = {};

  whann[tid] = 0.5f - 0.5f * cos_rev((float)tid * (1.0f / 512.0f));
  whann[tid + 256] = 0.5f - 0.5f * cos_rev((float)(tid + 256) * (1.0f / 512.0f));
  __syncthreads();

  auto load_a = [&](int kk) {
    const float* s0 = Af + (size_t)(m0 + srowA) * Kt + kk + skg * 8;
    float4 a0 = ((const float4*)s0)[0], a1 = ((const float4*)s0)[1];
    float4 w0 = *(const float4*)(&whann[kk + skg * 8]);
    float4 w1 = *(const float4*)(&whann[kk + skg * 8 + 4]);
    ra[0] = (_Float16)(a0.x * w0.x); ra[1] = (_Float16)(a0.y * w0.y);
    ra[2] = (_Float16)(a0.z * w0.z); ra[3] = (_Float16)(a0.w * w0.w);
    ra[4] = (_Float16)(a1.x * w1.x); ra[5] = (_Float16)(a1.y * w1.y);
    ra[6] = (_Float16)(a1.z * w1.z); ra[7] = (_Float16)(a1.w * w1.w);
    rb[0] = *(const half8*)(B + (size_t)(bn0 + srowB0) * Kt + kk + skg * 8);
    rb[1] = *(const half8*)(B + (size_t)(bn0 + srowB1) * Kt + kk + skg * 8);
  };
  auto store_lds = [&](int b) {
    *(half8*)(&Ash[b][srowA * 64 + ((skg ^ (srowA & 7)) << 3)]) = ra;
    *(half8*)(&Bsh[b][srowB0 * 64 + ((skg ^ (srowB0 & 7)) << 3)]) = rb[0];
    *(half8*)(&Bsh[b][srowB1 * 64 + ((skg ^ (srowB1 & 7)) << 3)]) = rb[1];
  };

  load_a(0);
  store_lds(0);

  for (int t = 0;;) {
    if (t + 1 < nT) load_a((t + 1) << 6);
    __syncthreads();
    const int b = t & 1;
#pragma unroll
    for (int ks = 0; ks < 2; ++ks) {
      const int kg = ks * 4 + q;
      const int ar = wr + r;
      half8 af = *(const half8*)(&Ash[b][ar * 64 + ((kg ^ (ar & 7)) << 3)]);
#pragma unroll
      for (int ni = 0; ni < 2; ++ni) {
        const int br = wc + ni * 16 + r;
        half8 bf = *(const half8*)(&Bsh[b][br * 64 + ((kg ^ (br & 7)) << 3)]);
        acc[ni] = __builtin_amdgcn_mfma_f32_16x16x32_f16(af, bf, acc[ni], 0, 0, 0);
      }
    }
    if (t + 1 >= nT) break;
    __syncthreads();
    store_lds((t + 1) & 1);
    ++t;
  }

  const float F0_DIFF = 780.0f / 11025.0f;
#pragma unroll
  for (int reg = 0; reg < 4; ++reg) {
    const int row = m0 + wr + q * 4 + reg;   // frame
    const float mu = f0_to_norm(f0[row], f0b[row >> 6]);
    const float sd = fminf(fmaxf(nstd[row], 1e-12f), 1.0f) * F0_DIFF;
    const float inv_sd = 1.0f / sd;
    const float a = inv_sd * (1.0f / 256.0f);
    const float bmu = mu * inv_sd;
#pragma unroll
    for (int ni = 0; ni < 2; ++ni) {
      const int col = bn0 + wc + ni * 16 + r;  // kappa
      const int k = col & 127;
      float z = fmaf((float)k, a, -bmu);
      float cf = (k == 0) ? (1.0f / 512.0f) : (2.0f / 512.0f);
      float s = cf * exp2f(z * z * -0.72134752044f);  // exp(-z^2/2)
      Cout[(size_t)row * 256 + col] = (_Float16)(acc[ni][reg] * s);
    }
  }
}

// ---------------------------------------------------------------------------
// Kernel 3: fused inverse DFT + OLA + oscillator bank + mix.
// 32-chunk M-tiles: grid 1024 = be(128) x chalf(2) x n0(4), XCD-swizzled so
// all 8 blocks of one be co-locate. 33-row A-tile; row 0 is zero only for
// chalf==0 (OLA does not cross (b,e) boundaries).
// ---------------------------------------------------------------------------
__global__ __launch_bounds__(256) void invfin_k(const _Float16* __restrict__ AB,
                                                const _Float16* __restrict__ W2,
                                                const float* __restrict__ f0,
                                                const float* __restrict__ f0b,
                                                const float* __restrict__ oenv_g,
                                                const float* __restrict__ oscenv_g,
                                                const float* __restrict__ henv_g,
                                                float* __restrict__ out) {
  const int p = blockIdx.x;                // [0,1024)
  const int x = p & 7, j = p >> 3;         // j in [0,128)
  const int be = ((j >> 3) << 3) + x;      // [0,128)
  const int sub = j & 7;
  const int chalf = sub >> 2;              // 0/1: chunk half
  const int n0 = (sub & 3) * 64;           // sample-within-chunk base
  const int m0c = be * 64 + chalf * 32;    // global chunk base of this tile
  const int tid = threadIdx.x;
  const int wave = tid >> 6, lane = tid & 63;
  const int r = lane & 15, q = lane >> 4;
  const int wr = (wave & 1) * 16;          // chunk-row sub-tile
  const int wc = (wave >> 1) * 32;         // sample-col sub-tile

  __shared__ __align__(16) _Float16 A2sh[33 * 64];   // chunks m0c-1 .. m0c+31
  __shared__ __align__(16) _Float16 B1sh[64 * 64];   // W2[n0+row]
  __shared__ __align__(16) _Float16 B2sh[64 * 64];   // W2[n0+row+256]
  __shared__ __align__(16) float4 qe4[8 * SEQ];
  __shared__ float oenv[SEQ], oscE[SEQ];
  __shared__ float Fs[SEQ], Ds[SEQ], Gs[SEQ];

  if (tid < SEQ) {
    oenv[tid] = clip01(oenv_g[be * SEQ + tid]);
    oscE[tid] = clip01(oscenv_g[be * SEQ + tid]);
    Fs[tid] = f0_to_norm(f0[be * SEQ + tid], f0b[be]);
  }
  __syncthreads();

  // wave 0: segment phase-prefix scan (f64, 6 shuffle steps), mod 2
  if (tid < SEQ) {
    const int s = tid;
    float fcur = Fs[s];
    float fnxt = (s < 63) ? Fs[s + 1] : Fs[63];
    Ds[s] = fnxt - fcur;                               // D[63] = 0
    double term = 128.0 * ((double)fcur + (double)fnxt);
    double sc = term;
#pragma unroll
    for (int off = 1; off < 64; off <<= 1) {
      double u = __shfl_up(sc, off, 64);
      if (s >= off) sc += u;
    }
    double C = 128.0 * (double)Fs[0] + (sc - term);    // exclusive prefix
    Gs[s] = (float)(C - 2.0 * floor(C * 0.5));
  }

  // stage qe4 (osc_env * harm_env)
  for (int idx = tid; idx < 8 * SEQ; idx += 256) {
    int hq = idx >> 6, s = idx & 63;
    const float* hb = henv_g + (size_t)be * (NHARM * SEQ) + (4 * hq) * SEQ + s;
    float e = oscE[s];
    qe4[idx] = make_float4(e * clip01(hb[0]), e * clip01(hb[64]),
                           e * clip01(hb[128]), e * clip01(hb[192]));
  }

  auto stage_AB = [&](int kk) {
    // A: 33 rows x 8 granules = 264 granule-stores
#pragma unroll
    for (int it = 0; it < 2; ++it) {
      int g = it * 256 + tid;
      if (g < 264) {
        int row = g >> 3, kg = g & 7;
        half8 v = {0, 0, 0, 0, 0, 0, 0, 0};
        if (row > 0 || chalf == 1)
          v = *(const half8*)(AB + (size_t)(m0c - 1 + row) * 256 + kk + kg * 8);
        *(half8*)(&A2sh[row * 64 + ((kg ^ (row & 7)) << 3)]) = v;
      }
    }
    // B1 + B2: 2 x 64 rows x 8 granules
#pragma unroll
    for (int it = 0; it < 4; ++it) {
      int g = it * 256 + tid;
      int row = (g >> 3) & 63, kg = g & 7;
      bool second = g >= 512;
      int wrow = n0 + row + (second ? 256 : 0);
      half8 v = *(const half8*)(W2 + (size_t)wrow * 256 + kk + kg * 8);
      _Float16* dst = second ? B2sh : B1sh;
      *(half8*)(&dst[row * 64 + ((kg ^ (row & 7)) << 3)]) = v;
    }
  };

  f32x4 acc[2] = {};
  stage_AB(0);
  __syncthreads();

  for (int t = 0;;) {
#pragma unroll
    for (int ks = 0; ks < 2; ++ks) {
      const int kg = ks * 4 + q;
      const int ra1 = 1 + wr + r;
      const int ra2 = wr + r;
      half8 af1 = *(const half8*)(&A2sh[ra1 * 64 + ((kg ^ (ra1 & 7)) << 3)]);
      half8 af2 = *(const half8*)(&A2sh[ra2 * 64 + ((kg ^ (ra2 & 7)) << 3)]);
#pragma unroll
      for (int ni = 0; ni < 2; ++ni) {
        const int rb = wc + ni * 16 + r;
        const int sw = (kg ^ (rb & 7)) << 3;
        half8 bf1 = *(const half8*)(&B1sh[rb * 64 + sw]);
        half8 bf2 = *(const half8*)(&B2sh[rb * 64 + sw]);
        acc[ni] = __builtin_amdgcn_mfma_f32_16x16x32_f16(af1, bf1, acc[ni], 0, 0, 0);
        acc[ni] = __builtin_amdgcn_mfma_f32_16x16x32_f16(af2, bf2, acc[ni], 0, 0, 0);
      }
    }
    if (t == 3) break;
    __syncthreads();
    stage_AB((t + 1) << 6);
    __syncthreads();
    ++t;
  }

  // epilogue: analytic phase + oscillator bank + mix, in-register
#pragma unroll
  for (int reg = 0; reg < 4; ++reg) {
    const int c = chalf * 32 + wr + q * 4 + reg;     // chunk within be
#pragma unroll
    for (int ni = 0; ni < 2; ++ni) {
      const int n = n0 + wc + ni * 16 + r;
      const int t = c * 256 + n;
      float pos = ((float)t + 0.5f) * (1.0f / 256.0f) - 0.5f;
      pos = fminf(fmaxf(pos, 0.0f), 63.0f);
      int i0 = (int)pos;
      int i1 = min(i0 + 1, 63);
      float w = pos - (float)i0;

      float pph;
      if (t < 128) {
        pph = (float)(t + 1) * Fs[0];
      } else {
        int s = (t - 128) >> 8;
        float u1 = (float)((t - 128) - (s << 8) + 1);
        pph = Gs[s] + fmaf(Ds[s] * (1.0f / 512.0f), u1 * u1, u1 * Fs[s]);
      }
      pph = pph - 2.0f * floorf(pph * 0.5f);         // phase mod 2 (pi units)
      float xv = pph * 0.5f;
      float sb = sin_rev(xv);
      float cb = cos_rev(xv);
      float C = 2.0f * cb;

      float fund = sb * (oscE[i0] * (1.0f - w) + oscE[i1] * w);
      float d0 = 0.0f, d1 = 0.0f;
      float sp = sb;
      float scur = C * sb;
#pragma unroll
      for (int hq = 0; hq < 8; ++hq) {
        float4 qa = qe4[hq * 64 + i0];
        float4 qb = qe4[hq * 64 + i1];
        d0 = fmaf(scur, qa.x, d0); d1 = fmaf(scur, qb.x, d1);
        sp = fmaf(C, scur, -sp);
        d0 = fmaf(sp, qa.y, d0);   d1 = fmaf(sp, qb.y, d1);
        scur = fmaf(C, sp, -scur);
        d0 = fmaf(scur, qa.z, d0); d1 = fmaf(scur, qb.z, d1);
        sp = fmaf(C, scur, -sp);
        d0 = fmaf(sp, qa.w, d0);   d1 = fmaf(sp, qb.w, d1);
        scur = fmaf(C, sp, -scur);
      }
      float osc = fund + d0 * (1.0f - w) + d1 * w;
      float mix = oenv[i0] * (1.0f - w) + oenv[i1] * w;
      out[(size_t)be * NSAMP + t] = fmaf(osc, mix, acc[ni][reg] * (1.0f - mix));
    }
  }
}

// ---------------------------------------------------------------------------
extern "C" void kernel_launch(void* const* d_in, const int* in_sizes, int n_in,
                              void* d_out, int out_size, void* d_ws, size_t ws_size,
                              hipStream_t stream) {
  const float* f0           = (const float*)d_in[0];
  const float* overall_env  = (const float*)d_in[1];
  const float* osc_env      = (const float*)d_in[2];
  // d_in[3] = noise_env: unused by the reference
  const float* harm_env     = (const float*)d_in[4];
  const float* noise_std    = (const float*)d_in[5];
  const float* f0_base      = (const float*)d_in[6];
  const float* noise_frames = (const float*)d_in[7];
  float* out = (float*)d_out;

  // workspace layout
  _Float16* W1 = (_Float16*)d_ws;                         // 131,072 f16
  _Float16* W2 = W1 + 256 * 512;                          // 131,072 f16
  _Float16* AB = W2 + 512 * 256;                          // 2,097,152 f16

  prep_k<<<256, 256, 0, stream>>>(W1);
  // fwd: AB = filt( hann(frames) x W1^T ) ; also generates W2 (blocks 0..255)
  gemmf_k<<<1280, 256, 0, stream>>>(noise_frames, W1, AB, W2, f0, noise_std, f0_base);
  // inv + OLA + oscillator bank + final mix, writes out directly
  invfin_k<<<1024, 256, 0, stream>>>(
      AB, W2, f0, f0_base, overall_env, osc_env, harm_env, out);
}

// Round 11
// 33.532 us; speedup vs baseline: 3.3466x; 1.0302x over previous
//
#include <hip/hip_runtime.h>
#include <math.h>

// ---- problem constants ----
#define SEQ 64
#define NSAMP 16384
#define NHARM 32
#define NWS 512
#define NSTEP 256
#define BE 128            // B*E = 8*16
#define NFRAMES 8192      // BE * SEQ

typedef _Float16 half8 __attribute__((ext_vector_type(8)));
typedef float f32x4 __attribute__((ext_vector_type(4)));

__device__ __forceinline__ float sin_rev(float x) {  // sin(2*pi*x)
  float r; asm("v_sin_f32 %0, %1" : "=v"(r) : "v"(x)); return r;
}
__device__ __forceinline__ float cos_rev(float x) {  // cos(2*pi*x)
  float r; asm("v_cos_f32 %0, %1" : "=v"(r) : "v"(x)); return r;
}
__device__ __forceinline__ float clip01(float v) { return fminf(fmaxf(v, 0.0f), 1.0f); }

__device__ __forceinline__ float f0_to_norm(float f0v, float bl) {
  const float NYQ = 11025.0f;
  const float MIN_F0 = 20.0f / 11025.0f;
  const float F0_DIFF = 780.0f / 11025.0f;
  float v = fminf(fmaxf(f0v, -0.5f), 0.5f);
  float erb = (0.108f * (bl * NYQ) + 24.7f) / NYQ;
  float fv = clip01(bl + v * erb);
  return MIN_F0 + fv * F0_DIFF;
}

// ---------------------------------------------------------------------------
// Kernel 1: forward GEMM (32x64 tiles, 4 blk/CU) + W2 table generation.
//   blocks [0,256):    W2[512][256] twiddles (2 rows/block; consumer is the
//                      NEXT launch -> no race).
//   blocks [256,1280): AB[8192][256] = filt( hann(frames) x W1^T ), f16 out.
//     W1 twiddles are GENERATED IN-LDS via trig (16 v_sin|v_cos per thread
//     per K-step) -- no W1 buffer, no prep launch. VALU cost hides under the
//     HBM-bound A stream. XCD swizzle: the 4 bn-blocks of one 32-frame
//     stripe share physical index mod 8 -> same XCD -> A re-reads L2-hit.
// ---------------------------------------------------------------------------
__global__ __launch_bounds__(256) void gemmf_k(const float* __restrict__ Af,
                                               _Float16* __restrict__ Cout,
                                               _Float16* __restrict__ W2,
                                               const float* __restrict__ f0,
                                               const float* __restrict__ nstd,
                                               const float* __restrict__ f0b) {
  const int tid = threadIdx.x;

  if (blockIdx.x < 256) {   // ---- W2 generation ----
    const int k = tid & 127;
    const bool isSin = tid >= 128;
#pragma unroll
    for (int rr = 0; rr < 2; ++rr) {
      const int n = blockIdx.x * 2 + rr;
      int a = (k * n) & 511;
      float ph = (float)a * (1.0f / 512.0f);
      W2[n * 256 + tid] = (_Float16)(isSin ? sin_rev(ph) : cos_rev(ph));
    }
    return;
  }

  // ---- GEMM: swizzled block decode (1024 blocks) ----
  const int p = blockIdx.x - 256;          // [0,1024)
  const int x = p & 7, j = p >> 3;         // j in [0,128)
  const int mstripe = ((j >> 2) << 3) + x; // [0,256)
  const int bn0 = (j & 3) * 64;
  const int m0 = mstripe * 32;

  const int Kt = 512;
  const int wave = tid >> 6, lane = tid & 63;
  const int r = lane & 15, q = lane >> 4;
  const int wr = (wave & 1) * 16;          // A-row (frame) sub-tile
  const int wc = (wave >> 1) * 32;         // B-row (kappa) sub-tile
  __shared__ __align__(16) _Float16 Ash[2][32 * 64];   // 8 KB
  __shared__ __align__(16) _Float16 Bsh[2][64 * 64];   // 16 KB
  __shared__ __align__(16) float whann[512];           // 2 KB

  const int nT = Kt >> 6;
  const int srowA = tid >> 3;              // 0..31 (one granule per thread)
  const int srowB0 = tid >> 3, srowB1 = (256 + tid) >> 3;
  const int skg = tid & 7;

  half8 ra, rb[2];
  f32x4 acc[2] = {};

  whann[tid] = 0.5f - 0.5f * cos_rev((float)tid * (1.0f / 512.0f));
  whann[tid + 256] = 0.5f - 0.5f * cos_rev((float)(tid + 256) * (1.0f / 512.0f));
  __syncthreads();

  // B-tile twiddle constants for this thread (uniform rows across K-steps)
  const int kB0 = (bn0 + srowB0) & 127;
  const int kB1 = (bn0 + srowB1) & 127;
  const bool sB0 = (bn0 + srowB0) >= 128;
  const bool sB1 = (bn0 + srowB1) >= 128;

  auto load_a = [&](int kk) {
    const float* s0 = Af + (size_t)(m0 + srowA) * Kt + kk + skg * 8;
    float4 a0 = ((const float4*)s0)[0], a1 = ((const float4*)s0)[1];
    float4 w0 = *(const float4*)(&whann[kk + skg * 8]);
    float4 w1 = *(const float4*)(&whann[kk + skg * 8 + 4]);
    ra[0] = (_Float16)(a0.x * w0.x); ra[1] = (_Float16)(a0.y * w0.y);
    ra[2] = (_Float16)(a0.z * w0.z); ra[3] = (_Float16)(a0.w * w0.w);
    ra[4] = (_Float16)(a1.x * w1.x); ra[5] = (_Float16)(a1.y * w1.y);
    ra[6] = (_Float16)(a1.z * w1.z); ra[7] = (_Float16)(a1.w * w1.w);
  };
  auto gen_b = [&](int kk) {  // W1 values via trig: bit-identical to table
    const int nbase = kk + skg * 8;
#pragma unroll
    for (int jj = 0; jj < 8; ++jj) {
      const int n = nbase + jj;
      float ph0 = (float)((kB0 * n) & 511) * (1.0f / 512.0f);
      float ph1 = (float)((kB1 * n) & 511) * (1.0f / 512.0f);
      rb[0][jj] = (_Float16)(sB0 ? sin_rev(ph0) : cos_rev(ph0));
      rb[1][jj] = (_Float16)(sB1 ? sin_rev(ph1) : cos_rev(ph1));
    }
  };
  auto store_lds = [&](int b) {
    *(half8*)(&Ash[b][srowA * 64 + ((skg ^ (srowA & 7)) << 3)]) = ra;
    *(half8*)(&Bsh[b][srowB0 * 64 + ((skg ^ (srowB0 & 7)) << 3)]) = rb[0];
    *(half8*)(&Bsh[b][srowB1 * 64 + ((skg ^ (srowB1 & 7)) << 3)]) = rb[1];
  };

  load_a(0);
  gen_b(0);
  store_lds(0);

  for (int t = 0;;) {
    if (t + 1 < nT) { load_a((t + 1) << 6); gen_b((t + 1) << 6); }
    __syncthreads();
    const int b = t & 1;
#pragma unroll
    for (int ks = 0; ks < 2; ++ks) {
      const int kg = ks * 4 + q;
      const int ar = wr + r;
      half8 af = *(const half8*)(&Ash[b][ar * 64 + ((kg ^ (ar & 7)) << 3)]);
#pragma unroll
      for (int ni = 0; ni < 2; ++ni) {
        const int br = wc + ni * 16 + r;
        half8 bf = *(const half8*)(&Bsh[b][br * 64 + ((kg ^ (br & 7)) << 3)]);
        acc[ni] = __builtin_amdgcn_mfma_f32_16x16x32_f16(af, bf, acc[ni], 0, 0, 0);
      }
    }
    if (t + 1 >= nT) break;
    __syncthreads();
    store_lds((t + 1) & 1);
    ++t;
  }

  const float F0_DIFF = 780.0f / 11025.0f;
#pragma unroll
  for (int reg = 0; reg < 4; ++reg) {
    const int row = m0 + wr + q * 4 + reg;   // frame
    const float mu = f0_to_norm(f0[row], f0b[row >> 6]);
    const float sd = fminf(fmaxf(nstd[row], 1e-12f), 1.0f) * F0_DIFF;
    const float inv_sd = 1.0f / sd;
    const float a = inv_sd * (1.0f / 256.0f);
    const float bmu = mu * inv_sd;
#pragma unroll
    for (int ni = 0; ni < 2; ++ni) {
      const int col = bn0 + wc + ni * 16 + r;  // kappa
      const int k = col & 127;
      float z = fmaf((float)k, a, -bmu);
      float cf = (k == 0) ? (1.0f / 512.0f) : (2.0f / 512.0f);
      float s = cf * exp2f(z * z * -0.72134752044f);  // exp(-z^2/2)
      Cout[(size_t)row * 256 + col] = (_Float16)(acc[ni][reg] * s);
    }
  }
}

// ---------------------------------------------------------------------------
// Kernel 2: fused inverse DFT + OLA + oscillator bank + mix.
// 32-chunk M-tiles, grid 1024 = be(128) x chalf(2) x n0(4), XCD-swizzled.
// T14 reg-staging: next K-step's A/W2 loads issue BEFORE the current MFMA
// (latency hides under compute), LDS write happens after the barrier.
// ---------------------------------------------------------------------------
__global__ __launch_bounds__(256) void invfin_k(const _Float16* __restrict__ AB,
                                                const _Float16* __restrict__ W2,
                                                const float* __restrict__ f0,
                                                const float* __restrict__ f0b,
                                                const float* __restrict__ oenv_g,
                                                const float* __restrict__ oscenv_g,
                                                const float* __restrict__ henv_g,
                                                float* __restrict__ out) {
  const int p = blockIdx.x;                // [0,1024)
  const int x = p & 7, j = p >> 3;         // j in [0,128)
  const int be = ((j >> 3) << 3) + x;      // [0,128)
  const int sub = j & 7;
  const int chalf = sub >> 2;              // 0/1: chunk half
  const int n0 = (sub & 3) * 64;           // sample-within-chunk base
  const int m0c = be * 64 + chalf * 32;    // global chunk base of this tile
  const int tid = threadIdx.x;
  const int wave = tid >> 6, lane = tid & 63;
  const int r = lane & 15, q = lane >> 4;
  const int wr = (wave & 1) * 16;          // chunk-row sub-tile
  const int wc = (wave >> 1) * 32;         // sample-col sub-tile

  __shared__ __align__(16) _Float16 A2sh[33 * 64];   // chunks m0c-1 .. m0c+31
  __shared__ __align__(16) _Float16 B1sh[64 * 64];   // W2[n0+row]
  __shared__ __align__(16) _Float16 B2sh[64 * 64];   // W2[n0+row+256]
  __shared__ __align__(16) float4 qe4[8 * SEQ];
  __shared__ float oenv[SEQ], oscE[SEQ];
  __shared__ float Fs[SEQ], Ds[SEQ], Gs[SEQ];

  if (tid < SEQ) {
    oenv[tid] = clip01(oenv_g[be * SEQ + tid]);
    oscE[tid] = clip01(oscenv_g[be * SEQ + tid]);
    Fs[tid] = f0_to_norm(f0[be * SEQ + tid], f0b[be]);
  }
  __syncthreads();

  // wave 0: segment phase-prefix scan (f64, 6 shuffle steps), mod 2
  if (tid < SEQ) {
    const int s = tid;
    float fcur = Fs[s];
    float fnxt = (s < 63) ? Fs[s + 1] : Fs[63];
    Ds[s] = fnxt - fcur;                               // D[63] = 0
    double term = 128.0 * ((double)fcur + (double)fnxt);
    double sc = term;
#pragma unroll
    for (int off = 1; off < 64; off <<= 1) {
      double u = __shfl_up(sc, off, 64);
      if (s >= off) sc += u;
    }
    double C = 128.0 * (double)Fs[0] + (sc - term);    // exclusive prefix
    Gs[s] = (float)(C - 2.0 * floor(C * 0.5));
  }

  // stage qe4 (osc_env * harm_env)
  for (int idx = tid; idx < 8 * SEQ; idx += 256) {
    int hq = idx >> 6, s = idx & 63;
    const float* hb = henv_g + (size_t)be * (NHARM * SEQ) + (4 * hq) * SEQ + s;
    float e = oscE[s];
    qe4[idx] = make_float4(e * clip01(hb[0]), e * clip01(hb[64]),
                           e * clip01(hb[128]), e * clip01(hb[192]));
  }

  // T14 staging state: A granule 0 (all threads) + A granule 1 (tid<8) + 4 B
  half8 raA0, raA1, rbB[4];
  const int rowA0 = tid >> 3, kgA0 = tid & 7;           // g = tid
  const int rowA1 = (256 + tid) >> 3, kgA1 = tid & 7;   // g = 256+tid (tid<8)

  auto stage_load = [&](int kk) {
    {
      half8 v = {0, 0, 0, 0, 0, 0, 0, 0};
      if (rowA0 > 0 || chalf == 1)
        v = *(const half8*)(AB + (size_t)(m0c - 1 + rowA0) * 256 + kk + kgA0 * 8);
      raA0 = v;
    }
    if (tid < 8)
      raA1 = *(const half8*)(AB + (size_t)(m0c - 1 + rowA1) * 256 + kk + kgA1 * 8);
#pragma unroll
    for (int it = 0; it < 4; ++it) {
      int g = it * 256 + tid;
      int row = (g >> 3) & 63;
      bool second = g >= 512;
      int wrow = n0 + row + (second ? 256 : 0);
      rbB[it] = *(const half8*)(W2 + (size_t)wrow * 256 + kk + (g & 7) * 8);
    }
  };
  auto stage_write = [&]() {
    *(half8*)(&A2sh[rowA0 * 64 + ((kgA0 ^ (rowA0 & 7)) << 3)]) = raA0;
    if (tid < 8)
      *(half8*)(&A2sh[rowA1 * 64 + ((kgA1 ^ (rowA1 & 7)) << 3)]) = raA1;
#pragma unroll
    for (int it = 0; it < 4; ++it) {
      int g = it * 256 + tid;
      int row = (g >> 3) & 63;
      _Float16* dst = (g >= 512) ? B2sh : B1sh;
      *(half8*)(&dst[row * 64 + (((g & 7) ^ (row & 7)) << 3)]) = rbB[it];
    }
  };

  f32x4 acc[2] = {};
  stage_load(0);
  stage_write();
  __syncthreads();

  for (int t = 0;;) {
    if (t < 3) stage_load((t + 1) << 6);   // issue loads; latency hides in MFMA
#pragma unroll
    for (int ks = 0; ks < 2; ++ks) {
      const int kg = ks * 4 + q;
      const int ra1 = 1 + wr + r;
      const int ra2 = wr + r;
      half8 af1 = *(const half8*)(&A2sh[ra1 * 64 + ((kg ^ (ra1 & 7)) << 3)]);
      half8 af2 = *(const half8*)(&A2sh[ra2 * 64 + ((kg ^ (ra2 & 7)) << 3)]);
#pragma unroll
      for (int ni = 0; ni < 2; ++ni) {
        const int rb = wc + ni * 16 + r;
        const int sw = (kg ^ (rb & 7)) << 3;
        half8 bf1 = *(const half8*)(&B1sh[rb * 64 + sw]);
        half8 bf2 = *(const half8*)(&B2sh[rb * 64 + sw]);
        acc[ni] = __builtin_amdgcn_mfma_f32_16x16x32_f16(af1, bf1, acc[ni], 0, 0, 0);
        acc[ni] = __builtin_amdgcn_mfma_f32_16x16x32_f16(af2, bf2, acc[ni], 0, 0, 0);
      }
    }
    if (t == 3) break;
    __syncthreads();
    stage_write();
    __syncthreads();
    ++t;
  }

  // epilogue: analytic phase + oscillator bank + mix, in-register
#pragma unroll
  for (int reg = 0; reg < 4; ++reg) {
    const int c = chalf * 32 + wr + q * 4 + reg;     // chunk within be
#pragma unroll
    for (int ni = 0; ni < 2; ++ni) {
      const int n = n0 + wc + ni * 16 + r;
      const int t = c * 256 + n;
      float pos = ((float)t + 0.5f) * (1.0f / 256.0f) - 0.5f;
      pos = fminf(fmaxf(pos, 0.0f), 63.0f);
      int i0 = (int)pos;
      int i1 = min(i0 + 1, 63);
      float w = pos - (float)i0;

      float pph;
      if (t < 128) {
        pph = (float)(t + 1) * Fs[0];
      } else {
        int s = (t - 128) >> 8;
        float u1 = (float)((t - 128) - (s << 8) + 1);
        pph = Gs[s] + fmaf(Ds[s] * (1.0f / 512.0f), u1 * u1, u1 * Fs[s]);
      }
      pph = pph - 2.0f * floorf(pph * 0.5f);         // phase mod 2 (pi units)
      float xv = pph * 0.5f;
      float sb = sin_rev(xv);
      float cb = cos_rev(xv);
      float C = 2.0f * cb;

      float fund = sb * (oscE[i0] * (1.0f - w) + oscE[i1] * w);
      float d0 = 0.0f, d1 = 0.0f;
      float sp = sb;
      float scur = C * sb;
#pragma unroll
      for (int hq = 0; hq < 8; ++hq) {
        float4 qa = qe4[hq * 64 + i0];
        float4 qb = qe4[hq * 64 + i1];
        d0 = fmaf(scur, qa.x, d0); d1 = fmaf(scur, qb.x, d1);
        sp = fmaf(C, scur, -sp);
        d0 = fmaf(sp, qa.y, d0);   d1 = fmaf(sp, qb.y, d1);
        scur = fmaf(C, sp, -scur);
        d0 = fmaf(scur, qa.z, d0); d1 = fmaf(scur, qb.z, d1);
        sp = fmaf(C, scur, -sp);
        d0 = fmaf(sp, qa.w, d0);   d1 = fmaf(sp, qb.w, d1);
        scur = fmaf(C, sp, -scur);
      }
      float osc = fund + d0 * (1.0f - w) + d1 * w;
      float mix = oenv[i0] * (1.0f - w) + oenv[i1] * w;
      out[(size_t)be * NSAMP + t] = fmaf(osc, mix, acc[ni][reg] * (1.0f - mix));
    }
  }
}

// ---------------------------------------------------------------------------
extern "C" void kernel_launch(void* const* d_in, const int* in_sizes, int n_in,
                              void* d_out, int out_size, void* d_ws, size_t ws_size,
                              hipStream_t stream) {
  const float* f0           = (const float*)d_in[0];
  const float* overall_env  = (const float*)d_in[1];
  const float* osc_env      = (const float*)d_in[2];
  // d_in[3] = noise_env: unused by the reference
  const float* harm_env     = (const float*)d_in[4];
  const float* noise_std    = (const float*)d_in[5];
  const float* f0_base      = (const float*)d_in[6];
  const float* noise_frames = (const float*)d_in[7];
  float* out = (float*)d_out;

  // workspace layout
  _Float16* W2 = (_Float16*)d_ws;                         // 131,072 f16
  _Float16* AB = W2 + 512 * 256;                          // 2,097,152 f16

  // fwd: AB = filt( hann(frames) x W1^T ), W1 generated in-LDS;
  //      blocks 0..255 also write the W2 table for the next launch
  gemmf_k<<<1280, 256, 0, stream>>>(noise_frames, AB, W2, f0, noise_std, f0_base);
  // inv + OLA + oscillator bank + final mix, writes out directly
  invfin_k<<<1024, 256, 0, stream>>>(
      AB, W2, f0, f0_base, overall_env, osc_env, harm_env, out);
}